// Round 4
// baseline (341.586 us; speedup 1.0000x reference)
//
#include <hip/hip_runtime.h>
#include <hip/hip_bf16.h>
#include <math.h>

typedef float f32x4 __attribute__((ext_vector_type(4)));
typedef int   i32x4 __attribute__((ext_vector_type(4)));
typedef short s16x8 __attribute__((ext_vector_type(8)));

#define NB 4
#define NC 512
#define NM 4096
#define NHEADS 8

__device__ __forceinline__ float b2f(unsigned short u) {
  union { unsigned int i; float f; } x; x.i = ((unsigned)u) << 16; return x.f;
}

// ---------------- transpose fp32 (b,512,4096) -> bf16 (b,4096,512) for x and y ----------------
__global__ __launch_bounds__(256) void transpose_k(
    const float* __restrict__ x, const float* __restrict__ y,
    __hip_bfloat16* __restrict__ xT, __hip_bfloat16* __restrict__ yT)
{
  __shared__ __hip_bfloat16 tile[64][65];
  int z = blockIdx.z;                       // 0..3 x batches, 4..7 y batches
  const float* src = ((z < 4) ? x : y) + (long)(z & 3) * ((long)NC * NM);
  __hip_bfloat16* dst = (z < 4 ? xT : yT) + (long)(z & 3) * ((long)NC * NM);
  int tm = blockIdx.x * 64, tc = blockIdx.y * 64;
  int tx = threadIdx.x & 63, ty = threadIdx.x >> 6;
  #pragma unroll
  for (int p = 0; p < 16; p++) {
    int row = ty + p * 4;                   // c-local
    tile[row][tx] = __float2bfloat16(src[(long)(tc + row) * NM + tm + tx]);
  }
  __syncthreads();
  #pragma unroll
  for (int p = 0; p < 16; p++) {
    int row = ty + p * 4;                   // m-local
    dst[(long)(tm + row) * NC + tc + tx] = tile[tx][row];
  }
}

// ---------------- pack w_dw fp32 (o,i,3,3) -> bf16 Wr[r][o][i] ----------------
__global__ __launch_bounds__(256) void pack_wdw(
    const float* __restrict__ wdw, __hip_bfloat16* __restrict__ Wr)
{
  long idx = (long)blockIdx.x * 256 + threadIdx.x;   // over 9*512*512
  if (idx < 9L * 512 * 512) {
    int r = (int)(idx >> 18);
    int rem = (int)(idx & 262143);
    int o = rem >> 9, i = rem & 511;
    Wr[idx] = __float2bfloat16(wdw[((long)o * 512 + i) * 9 + r]);
  }
}

// ---------------- convert w_kv (1024x512) and w_q (512x512) fp32 -> bf16 ----------------
__global__ __launch_bounds__(256) void convert_w(
    const float* __restrict__ wkv, const float* __restrict__ wq,
    __hip_bfloat16* __restrict__ wkvB, __hip_bfloat16* __restrict__ wqB)
{
  long idx = (long)blockIdx.x * 256 + threadIdx.x;   // over 524288 + 262144
  if (idx < 524288) {
    wkvB[idx] = __float2bfloat16(wkv[idx]);
  } else if (idx < 524288 + 262144) {
    long j = idx - 524288;
    wqB[j] = __float2bfloat16(wq[j]);
  }
}

// ---------------- generic GEMM: C[M,N] = A[M,K] * B[N,K]^T (row-major bf16, fp32 acc) ----------------
// requires M%128==0, N%128==0, K%32==0. LDS stride 40 (=5x16B) avoids bank conflicts.
// outF32: write fp32 to Cf instead of bf16 to Cb.
__global__ __launch_bounds__(256) void gemm_bt(
    const __hip_bfloat16* __restrict__ Aall, long sA,
    const __hip_bfloat16* __restrict__ Ball, long sB,
    __hip_bfloat16* __restrict__ Cball, float* __restrict__ Cfall, long sC,
    int M, int N, int Kd, int outF32)
{
  const __hip_bfloat16* A = Aall + (long)blockIdx.z * sA;
  const __hip_bfloat16* B = Ball + (long)blockIdx.z * sB;
  const int m0 = blockIdx.y * 128, n0 = blockIdx.x * 128;
  __shared__ __hip_bfloat16 As[128 * 40];
  __shared__ __hip_bfloat16 Bs[128 * 40];
  const int tid = threadIdx.x;
  const int wid = tid >> 6, lane = tid & 63;
  const int wm = (wid >> 1) * 64, wn = (wid & 1) * 64;
  const int quad = lane >> 4, l16 = lane & 15;
  const int srow = tid >> 2, scol = (tid & 3) * 8;
  f32x4 acc[4][4] = {};
  const __hip_bfloat16* pA0 = A + (long)(m0 + srow) * Kd + scol;
  const __hip_bfloat16* pA1 = pA0 + (long)64 * Kd;
  const __hip_bfloat16* pB0 = B + (long)(n0 + srow) * Kd + scol;
  const __hip_bfloat16* pB1 = pB0 + (long)64 * Kd;
  i32x4 va0 = *(const i32x4*)(pA0);
  i32x4 va1 = *(const i32x4*)(pA1);
  i32x4 vb0 = *(const i32x4*)(pB0);
  i32x4 vb1 = *(const i32x4*)(pB1);
  for (int k0 = 0; k0 < Kd; k0 += 32) {
    __syncthreads();
    *(i32x4*)(&As[srow * 40 + scol])        = va0;
    *(i32x4*)(&As[(srow + 64) * 40 + scol]) = va1;
    *(i32x4*)(&Bs[srow * 40 + scol])        = vb0;
    *(i32x4*)(&Bs[(srow + 64) * 40 + scol]) = vb1;
    if (k0 + 32 < Kd) {            // prefetch next chunk; latency hides behind MFMAs
      va0 = *(const i32x4*)(pA0 + k0 + 32);
      va1 = *(const i32x4*)(pA1 + k0 + 32);
      vb0 = *(const i32x4*)(pB0 + k0 + 32);
      vb1 = *(const i32x4*)(pB1 + k0 + 32);
    }
    __syncthreads();
    s16x8 bfr[4];
    #pragma unroll
    for (int j = 0; j < 4; j++)
      bfr[j] = *(const s16x8*)(&Bs[(wn + j * 16 + l16) * 40 + quad * 8]);
    #pragma unroll
    for (int i = 0; i < 4; i++) {
      s16x8 af = *(const s16x8*)(&As[(wm + i * 16 + l16) * 40 + quad * 8]);
      #pragma unroll
      for (int j = 0; j < 4; j++)
        acc[i][j] = __builtin_amdgcn_mfma_f32_16x16x32_bf16(af, bfr[j], acc[i][j], 0, 0, 0);
    }
  }
  if (outF32) {
    float* C = Cfall + (long)blockIdx.z * sC;
    #pragma unroll
    for (int i = 0; i < 4; i++)
      #pragma unroll
      for (int j = 0; j < 4; j++) {
        int rbase = m0 + wm + i * 16 + quad * 4;
        int col = n0 + wn + j * 16 + l16;
        #pragma unroll
        for (int r = 0; r < 4; r++)
          C[(long)(rbase + r) * N + col] = acc[i][j][r];
      }
  } else {
    __hip_bfloat16* C = Cball + (long)blockIdx.z * sC;
    #pragma unroll
    for (int i = 0; i < 4; i++)
      #pragma unroll
      for (int j = 0; j < 4; j++) {
        int rbase = m0 + wm + i * 16 + quad * 4;
        int col = n0 + wn + j * 16 + l16;
        #pragma unroll
        for (int r = 0; r < 4; r++)
          C[(long)(rbase + r) * N + col] = __float2bfloat16(acc[i][j][r]);
      }
  }
}

// ---------------- 3x3 conv as implicit GEMM ----------------
// q2[b][o][hw] = sum_{r,i} Wr[r][o][i] * q1t[b][hw+shift(r)][i], zero-padded 64x64 image
__global__ __launch_bounds__(256) void conv3x3(
    const __hip_bfloat16* __restrict__ Wr,   // [9][512][512]
    const __hip_bfloat16* __restrict__ q1t,  // [b][4096][512]
    __hip_bfloat16* __restrict__ q2)         // [b][512][4096]
{
  const int b = blockIdx.z;
  const int n0 = blockIdx.x * 128;   // hw tile (2 image rows)
  const int m0 = blockIdx.y * 128;   // o tile
  __shared__ __hip_bfloat16 As[128 * 40];
  __shared__ __hip_bfloat16 Bs[256 * 40];    // 4 haloed image rows x 32 chans
  const int tid = threadIdx.x;
  const int wid = tid >> 6, lane = tid & 63;
  const int wm = (wid >> 1) * 64, wn = (wid & 1) * 64;
  const int quad = lane >> 4, l16 = lane & 15;
  const int srow = tid >> 2, scol = (tid & 3) * 8;
  const int h0 = n0 >> 6;
  const __hip_bfloat16* qb = q1t + (long)b * NM * NC;
  f32x4 acc[4][4] = {};
  const s16x8 zero8 = {0, 0, 0, 0, 0, 0, 0, 0};

  for (int ic = 0; ic < 512; ic += 32) {
    __syncthreads();
    // stage B: image rows h0-1 .. h0+2 (zero outside image), channels ic..ic+32
    #pragma unroll
    for (int rr = 0; rr < 4; rr++) {
      int p = rr * 64 + srow;                 // 0..255
      int hw = (h0 - 1) * 64 + p;
      i32x4 val = {};
      if (hw >= 0 && hw < NM) val = *(const i32x4*)(&qb[(long)hw * NC + ic + scol]);
      *(i32x4*)(&Bs[p * 40 + scol]) = val;
    }
    for (int r = 0; r < 9; r++) {
      int dy = r / 3 - 1, dx = r % 3 - 1;
      __syncthreads();   // prev reads of As (and for r==0, Bs stores) complete
      *(i32x4*)(&As[srow * 40 + scol]) =
          *(const i32x4*)(&Wr[((long)r * 512 + m0 + srow) * 512 + ic + scol]);
      *(i32x4*)(&As[(srow + 64) * 40 + scol]) =
          *(const i32x4*)(&Wr[((long)r * 512 + m0 + srow + 64) * 512 + ic + scol]);
      __syncthreads();
      s16x8 bfr[4];
      #pragma unroll
      for (int j = 0; j < 4; j++) {
        int nl = wn + j * 16 + l16;
        int wq = nl & 63, hr = nl >> 6;
        int wp = wq + dx;
        bool v = ((unsigned)wp) < 64u;        // w-boundary mask
        int p = v ? ((hr + 1 + dy) * 64 + wp) : 0;
        s16x8 t = *(const s16x8*)(&Bs[p * 40 + quad * 8]);
        bfr[j] = v ? t : zero8;
      }
      #pragma unroll
      for (int i = 0; i < 4; i++) {
        s16x8 af = *(const s16x8*)(&As[(wm + i * 16 + l16) * 40 + quad * 8]);
        #pragma unroll
        for (int j = 0; j < 4; j++)
          acc[i][j] = __builtin_amdgcn_mfma_f32_16x16x32_bf16(af, bfr[j], acc[i][j], 0, 0, 0);
      }
    }
  }
  __hip_bfloat16* Cb = q2 + (long)b * NC * NM;
  #pragma unroll
  for (int i = 0; i < 4; i++) {
    #pragma unroll
    for (int j = 0; j < 4; j++) {
      int rbase = m0 + wm + i * 16 + quad * 4;
      int col = n0 + wn + j * 16 + l16;
      #pragma unroll
      for (int r = 0; r < 4; r++)
        Cb[(long)(rbase + r) * NM + col] = __float2bfloat16(acc[i][j][r]);
    }
  }
}

// ---------------- per-row L2 norm (4096 bf16/row) -> max(sqrt(sumsq), 1e-12) ----------------
__global__ __launch_bounds__(256) void rowsumsq(
    const __hip_bfloat16* __restrict__ X, float* __restrict__ out)
{
  long row = blockIdx.x;
  const __hip_bfloat16* p = X + row * (long)NM + threadIdx.x * 16;
  union { i32x4 v; unsigned short u[8]; } a, b;
  a.v = *(const i32x4*)(p);
  b.v = *(const i32x4*)(p + 8);
  float s = 0.f;
  #pragma unroll
  for (int t = 0; t < 8; t++) {
    float f0 = b2f(a.u[t]); s += f0 * f0;
    float f1 = b2f(b.u[t]); s += f1 * f1;
  }
  #pragma unroll
  for (int off = 32; off > 0; off >>= 1) s += __shfl_down(s, off);
  __shared__ float red[4];
  if ((threadIdx.x & 63) == 0) red[threadIdx.x >> 6] = s;
  __syncthreads();
  if (threadIdx.x == 0)
    out[row] = fmaxf(sqrtf(red[0] + red[1] + red[2] + red[3]), 1e-12f);
}

// ---------------- attention logits partial: Gpart[b,h,mc][c][d] over m-chunk ----------------
__global__ __launch_bounds__(256) void attn_g(
    const __hip_bfloat16* __restrict__ q2, const __hip_bfloat16* __restrict__ Kb,
    float* __restrict__ Gpart)
{
  const int mc = blockIdx.x, h = blockIdx.y, b = blockIdx.z;
  const __hip_bfloat16* qrow = q2 + ((long)b * NC + h * 64) * NM + mc * 512;
  const __hip_bfloat16* krow = Kb + ((long)b * NC + h * 64) * NM + mc * 512;
  __shared__ __hip_bfloat16 Qs[64 * 40];
  __shared__ __hip_bfloat16 Ks[64 * 40];
  const int tid = threadIdx.x;
  const int wid = tid >> 6, lane = tid & 63;
  const int wc = (wid >> 1) * 32, wd = (wid & 1) * 32;
  const int quad = lane >> 4, l16 = lane & 15;
  const int srow = tid >> 2, scol = (tid & 3) * 8;
  f32x4 acc[2][2] = {};
  for (int k0 = 0; k0 < 512; k0 += 32) {
    __syncthreads();
    *(i32x4*)(&Qs[srow * 40 + scol]) = *(const i32x4*)(&qrow[(long)srow * NM + k0 + scol]);
    *(i32x4*)(&Ks[srow * 40 + scol]) = *(const i32x4*)(&krow[(long)srow * NM + k0 + scol]);
    __syncthreads();
    s16x8 bfr[2];
    #pragma unroll
    for (int j = 0; j < 2; j++)
      bfr[j] = *(const s16x8*)(&Ks[(wd + j * 16 + l16) * 40 + quad * 8]);
    #pragma unroll
    for (int i = 0; i < 2; i++) {
      s16x8 af = *(const s16x8*)(&Qs[(wc + i * 16 + l16) * 40 + quad * 8]);
      #pragma unroll
      for (int j = 0; j < 2; j++)
        acc[i][j] = __builtin_amdgcn_mfma_f32_16x16x32_bf16(af, bfr[j], acc[i][j], 0, 0, 0);
    }
  }
  float* gp = Gpart + ((long)((b * 8 + h) * 8 + mc)) * 4096;
  #pragma unroll
  for (int i = 0; i < 2; i++)
    #pragma unroll
    for (int j = 0; j < 2; j++)
      #pragma unroll
      for (int r = 0; r < 4; r++)
        gp[(wc + i * 16 + quad * 4 + r) * 64 + wd + j * 16 + l16] = acc[i][j][r];
}

// ---------------- sum partials, normalize, temperature, softmax over d ----------------
__global__ __launch_bounds__(256) void softmax_attn(
    const float* __restrict__ Gpart, const float* __restrict__ qn,
    const float* __restrict__ kn, const float* __restrict__ temp,
    float* __restrict__ attn)
{
  const int h = blockIdx.x, b = blockIdx.y;
  __shared__ float G[64][64];
  const int tid = threadIdx.x;
  const float tv = temp[h];
  for (int e = tid; e < 4096; e += 256) {
    float s = 0.f;
    #pragma unroll
    for (int p = 0; p < 8; p++)
      s += Gpart[((long)((b * 8 + h) * 8 + p)) * 4096 + e];
    int c = e >> 6, d = e & 63;
    float scale = tv / (qn[b * 512 + h * 64 + c] * kn[b * 512 + h * 64 + d]);
    G[c][d] = s * scale;
  }
  __syncthreads();
  int row = tid >> 2, s4 = tid & 3;
  float mx = -1e30f;
  for (int d = s4; d < 64; d += 4) mx = fmaxf(mx, G[row][d]);
  mx = fmaxf(mx, __shfl_xor(mx, 1));
  mx = fmaxf(mx, __shfl_xor(mx, 2));
  float sum = 0.f;
  for (int d = s4; d < 64; d += 4) { float e = __expf(G[row][d] - mx); G[row][d] = e; sum += e; }
  sum += __shfl_xor(sum, 1);
  sum += __shfl_xor(sum, 2);
  float inv = 1.f / sum;
  float* ap = attn + ((long)(b * 8 + h)) * 4096;
  for (int d = s4; d < 64; d += 4) ap[row * 64 + d] = G[row][d] * inv;
}

// ---------------- Wa[b][o][h*64+d] = sum_c w_out[o][h*64+c] * attn[b,h,c,d] ----------------
__global__ __launch_bounds__(256) void wa_kernel(
    const float* __restrict__ attn, const float* __restrict__ wout,
    __hip_bfloat16* __restrict__ Wa)
{
  const int oc = blockIdx.x, h = blockIdx.y, b = blockIdx.z;
  __shared__ float At[64][64];
  __shared__ float Wt[64][65];
  const int tid = threadIdx.x;
  const float* ap = attn + ((long)(b * 8 + h)) * 4096;
  for (int e = tid; e < 4096; e += 256) {
    At[e >> 6][e & 63] = ap[e];
    Wt[e >> 6][e & 63] = wout[(long)(oc * 64 + (e >> 6)) * 512 + h * 64 + (e & 63)];
  }
  __syncthreads();
  int d = tid & 63, og = tid >> 6;
  #pragma unroll
  for (int k = 0; k < 16; k++) {
    int o = og * 16 + k;
    float s = 0.f;
    #pragma unroll 8
    for (int c = 0; c < 64; c++) s += Wt[o][c] * At[c][d];
    Wa[((long)b * 512 + oc * 64 + o) * 512 + h * 64 + d] = __float2bfloat16(s);
  }
}

extern "C" void kernel_launch(void* const* d_in, const int* in_sizes, int n_in,
                              void* d_out, int out_size, void* d_ws, size_t ws_size,
                              hipStream_t stream) {
  const float* x    = (const float*)d_in[0];
  const float* y    = (const float*)d_in[1];
  const float* temp = (const float*)d_in[2];
  const float* wkv  = (const float*)d_in[3];
  const float* wq   = (const float*)d_in[4];
  const float* wdw  = (const float*)d_in[5];
  const float* wout = (const float*)d_in[6];
  float* out = (float*)d_out;     // fp32 output, per reference dtype

  char* ws = (char*)d_ws;
  const long TEN = 16777216;  // one (4,512,4096) bf16 tensor, bytes
  __hip_bfloat16* xT  = (__hip_bfloat16*)(ws);               // later reused as q2
  __hip_bfloat16* q2  = xT;                                  // alias: xT dead after Vt GEMM
  __hip_bfloat16* yT  = (__hip_bfloat16*)(ws + TEN);         // reused after q1 GEMM:
  float* Gpart        = (float*)(ws + TEN);                  //   4 MB
  float* attn         = (float*)(ws + TEN + 4194304);        //   512 KB
  __hip_bfloat16* Wa  = (__hip_bfloat16*)(ws + TEN + 4718592);   // 2 MB
  float* knorm        = (float*)(ws + TEN + 6815744);        //   8 KB
  float* qnorm        = (float*)(ws + TEN + 6823936);        //   8 KB
  __hip_bfloat16* Kb  = (__hip_bfloat16*)(ws + 2 * TEN);
  __hip_bfloat16* Vt  = (__hip_bfloat16*)(ws + 3 * TEN);
  __hip_bfloat16* q1t = (__hip_bfloat16*)(ws + 4 * TEN);
  __hip_bfloat16* Wr  = (__hip_bfloat16*)(ws + 5 * TEN);     // 4.5 MB
  __hip_bfloat16* wkvB = (__hip_bfloat16*)(ws + 5 * TEN + 4718592);  // 1 MB
  __hip_bfloat16* wqB  = (__hip_bfloat16*)(ws + 5 * TEN + 5767168);  // 512 KB

  const long S = (long)4096 * 512;  // per-batch tensor stride (elements)
  dim3 blk(256);

  pack_wdw<<<dim3(9216), blk, 0, stream>>>(wdw, Wr);
  convert_w<<<dim3(3072), blk, 0, stream>>>(wkv, wq, wkvB, wqB);
  transpose_k<<<dim3(64, 8, 8), blk, 0, stream>>>(x, y, xT, yT);
  // K[b][c][m] = w_k . x
  gemm_bt<<<dim3(32, 4, 4), blk, 0, stream>>>(wkvB, 0L, xT, S, Kb, nullptr, S, 512, 4096, 512, 0);
  // Vt[b][m][c] = x^T . w_v^T
  gemm_bt<<<dim3(4, 32, 4), blk, 0, stream>>>(xT, S, wkvB + 512 * 512, 0L, Vt, nullptr, S, 4096, 512, 512, 0);
  // q1t[b][hw][o] = y^T . w_q^T
  gemm_bt<<<dim3(4, 32, 4), blk, 0, stream>>>(yT, S, wqB, 0L, q1t, nullptr, S, 4096, 512, 512, 0);
  // q2[b][o][hw] = conv3x3(q1)   (interp L==M is identity)
  conv3x3<<<dim3(32, 4, 4), blk, 0, stream>>>(Wr, q1t, q2);
  rowsumsq<<<dim3(2048), blk, 0, stream>>>(Kb, knorm);
  rowsumsq<<<dim3(2048), blk, 0, stream>>>(q2, qnorm);
  attn_g<<<dim3(8, 8, 4), blk, 0, stream>>>(q2, Kb, Gpart);
  softmax_attn<<<dim3(8, 4), blk, 0, stream>>>(Gpart, qnorm, knorm, temp, attn);
  wa_kernel<<<dim3(8, 8, 4), blk, 0, stream>>>(attn, wout, Wa);
  // out[b][o][m] = Wa[b] . Vt[b]^T   -> fp32 d_out
  gemm_bt<<<dim3(32, 4, 4), blk, 0, stream>>>(Wa, (long)512 * 512, Vt, S, nullptr, out, S, 512, 4096, 512, 1);
  (void)in_sizes; (void)n_in; (void)out_size; (void)ws_size;
}

// Round 5
// 321.505 us; speedup vs baseline: 1.0625x; 1.0625x over previous
//
#include <hip/hip_runtime.h>
#include <hip/hip_bf16.h>
#include <math.h>

typedef float f32x4 __attribute__((ext_vector_type(4)));
typedef int   i32x4 __attribute__((ext_vector_type(4)));
typedef short s16x8 __attribute__((ext_vector_type(8)));

#define NB 4
#define NC 512
#define NM 4096
#define NHEADS 8

// async global->LDS, 16B per lane, LDS dest = wave-uniform base + lane*16
#define GLDS16(src, dst) __builtin_amdgcn_global_load_lds( \
    (const __attribute__((address_space(1))) void*)(src),  \
    (__attribute__((address_space(3))) void*)(dst), 16, 0, 0)

__device__ __forceinline__ float b2f(unsigned short u) {
  union { unsigned int i; float f; } x; x.i = ((unsigned)u) << 16; return x.f;
}

// ---------------- transpose fp32 (b,512,4096) -> bf16 (b,4096,512) for x and y ----------------
__global__ __launch_bounds__(256) void transpose_k(
    const float* __restrict__ x, const float* __restrict__ y,
    __hip_bfloat16* __restrict__ xT, __hip_bfloat16* __restrict__ yT)
{
  __shared__ __hip_bfloat16 tile[64][65];
  int z = blockIdx.z;                       // 0..3 x batches, 4..7 y batches
  const float* src = ((z < 4) ? x : y) + (long)(z & 3) * ((long)NC * NM);
  __hip_bfloat16* dst = (z < 4 ? xT : yT) + (long)(z & 3) * ((long)NC * NM);
  int tm = blockIdx.x * 64, tc = blockIdx.y * 64;
  int tx = threadIdx.x & 63, ty = threadIdx.x >> 6;
  #pragma unroll
  for (int p = 0; p < 16; p++) {
    int row = ty + p * 4;                   // c-local
    tile[row][tx] = __float2bfloat16(src[(long)(tc + row) * NM + tm + tx]);
  }
  __syncthreads();
  #pragma unroll
  for (int p = 0; p < 16; p++) {
    int row = ty + p * 4;                   // m-local
    dst[(long)(tm + row) * NC + tc + tx] = tile[tx][row];
  }
}

// ---------------- pack w_dw fp32 (o,i,3,3) -> bf16 Wr[r][o][i] ----------------
__global__ __launch_bounds__(256) void pack_wdw(
    const float* __restrict__ wdw, __hip_bfloat16* __restrict__ Wr)
{
  long idx = (long)blockIdx.x * 256 + threadIdx.x;   // over 9*512*512
  if (idx < 9L * 512 * 512) {
    int r = (int)(idx >> 18);
    int rem = (int)(idx & 262143);
    int o = rem >> 9, i = rem & 511;
    Wr[idx] = __float2bfloat16(wdw[((long)o * 512 + i) * 9 + r]);
  }
}

// ---------------- convert w_kv -> bf16; w_q -> bf16 TRANSPOSED (wqT[c][c'] = wq[c'][c]) ----------------
__global__ __launch_bounds__(256) void convert_w(
    const float* __restrict__ wkv, const float* __restrict__ wq,
    __hip_bfloat16* __restrict__ wkvB, __hip_bfloat16* __restrict__ wqT)
{
  long idx = (long)blockIdx.x * 256 + threadIdx.x;   // over 524288 + 262144
  if (idx < 524288) {
    wkvB[idx] = __float2bfloat16(wkv[idx]);
  } else if (idx < 524288 + 262144) {
    long j = idx - 524288;
    int c = (int)(j >> 9), cp = (int)(j & 511);
    wqT[j] = __float2bfloat16(wq[(long)cp * 512 + c]);
  }
}

// ---------------- generic GEMM: C[M,N] = A[M,K] * B[N,K]^T (row-major bf16, fp32 acc) ----------------
// m97-style: global_load_lds(16B) staging into unpadded [128][32] LDS tiles.
// requires M%128==0, N%128==0, K%32==0. outF32: write fp32 to Cf else bf16 to Cb.
__global__ __launch_bounds__(256) void gemm_bt(
    const __hip_bfloat16* __restrict__ Aall, long sA,
    const __hip_bfloat16* __restrict__ Ball, long sB,
    __hip_bfloat16* __restrict__ Cball, float* __restrict__ Cfall, long sC,
    int M, int N, int Kd, int outF32)
{
  const __hip_bfloat16* A = Aall + (long)blockIdx.z * sA;
  const __hip_bfloat16* B = Ball + (long)blockIdx.z * sB;
  const int m0 = blockIdx.y * 128, n0 = blockIdx.x * 128;
  __shared__ __hip_bfloat16 As[128 * 32];
  __shared__ __hip_bfloat16 Bs[128 * 32];
  const int tid = threadIdx.x;
  const int wid = tid >> 6, lane = tid & 63;
  const int wm = (wid >> 1) * 64, wn = (wid & 1) * 64;
  const int quad = lane >> 4, l16 = lane & 15;
  const int srow = wid * 32 + (lane >> 2);   // staging row (this wave covers 32 rows, 2 instrs)
  const int scol = (lane & 3) * 8;           // staging col (8 bf16 = 16B)
  f32x4 acc[4][4] = {};
  for (int k0 = 0; k0 < Kd; k0 += 32) {
    __syncthreads();
    #pragma unroll
    for (int t = 0; t < 2; t++) {
      GLDS16(A + (long)(m0 + srow + t * 16) * Kd + k0 + scol,
             As + (wid * 32 + t * 16) * 32);
      GLDS16(B + (long)(n0 + srow + t * 16) * Kd + k0 + scol,
             Bs + (wid * 32 + t * 16) * 32);
    }
    __builtin_amdgcn_s_waitcnt(0);
    __syncthreads();
    s16x8 bfr[4];
    #pragma unroll
    for (int j = 0; j < 4; j++)
      bfr[j] = *(const s16x8*)(&Bs[(wn + j * 16 + l16) * 32 + quad * 8]);
    #pragma unroll
    for (int i = 0; i < 4; i++) {
      s16x8 af = *(const s16x8*)(&As[(wm + i * 16 + l16) * 32 + quad * 8]);
      #pragma unroll
      for (int j = 0; j < 4; j++)
        acc[i][j] = __builtin_amdgcn_mfma_f32_16x16x32_bf16(af, bfr[j], acc[i][j], 0, 0, 0);
    }
  }
  if (outF32) {
    float* C = Cfall + (long)blockIdx.z * sC;
    #pragma unroll
    for (int i = 0; i < 4; i++)
      #pragma unroll
      for (int j = 0; j < 4; j++) {
        int rbase = m0 + wm + i * 16 + quad * 4;
        int col = n0 + wn + j * 16 + l16;
        #pragma unroll
        for (int r = 0; r < 4; r++)
          C[(long)(rbase + r) * N + col] = acc[i][j][r];
      }
  } else {
    __hip_bfloat16* C = Cball + (long)blockIdx.z * sC;
    #pragma unroll
    for (int i = 0; i < 4; i++)
      #pragma unroll
      for (int j = 0; j < 4; j++) {
        int rbase = m0 + wm + i * 16 + quad * 4;
        int col = n0 + wn + j * 16 + l16;
        #pragma unroll
        for (int r = 0; r < 4; r++)
          C[(long)(rbase + r) * N + col] = __float2bfloat16(acc[i][j][r]);
      }
  }
}

// ---------------- 3x3 conv as implicit GEMM (w_q folded into weights) ----------------
// q2[b][o][hw] = sum_{r,c} Wt[r][o][c] * yT[b][hw+shift(r)][c], zero-padded 64x64 image.
// global_load_lds staging; A staged in 3-tap groups (dy fixed) -> 6 barriers per ic-chunk.
__global__ __launch_bounds__(256) void conv3x3(
    const __hip_bfloat16* __restrict__ Wt,   // [9][512][512] folded weights
    const __hip_bfloat16* __restrict__ yT,   // [b][4096][512]
    const __hip_bfloat16* __restrict__ zeropad,  // >=64B of zeros
    __hip_bfloat16* __restrict__ q2)         // [b][512][4096]
{
  const int b = blockIdx.z;
  const int n0 = blockIdx.x * 128;   // hw tile (2 image rows)
  const int m0 = blockIdx.y * 128;   // o tile
  __shared__ __hip_bfloat16 As3[3 * 128 * 32];   // 24 KB: 3 taps of weights
  __shared__ __hip_bfloat16 Bs[256 * 32];        // 16 KB: 4 haloed image rows
  const int tid = threadIdx.x;
  const int wid = tid >> 6, lane = tid & 63;
  const int wm = (wid >> 1) * 64, wn = (wid & 1) * 64;
  const int quad = lane >> 4, l16 = lane & 15;
  const int lrow = lane >> 2, scol = (lane & 3) * 8;
  const int h0 = n0 >> 6;
  const __hip_bfloat16* yb = yT + (long)b * NM * NC;
  f32x4 acc[4][4] = {};
  const s16x8 zero8 = {0, 0, 0, 0, 0, 0, 0, 0};

  for (int ic = 0; ic < 512; ic += 32) {
    #pragma unroll
    for (int g = 0; g < 3; g++) {            // dy = g-1
      __syncthreads();                       // readers of As3 (and Bs at g==0) done
      if (g == 0) {
        // stage B: image rows h0-1 .. h0+2 (zero outside), channels ic..ic+31
        #pragma unroll
        for (int t = 0; t < 4; t++) {
          int p = wid * 64 + t * 16 + lrow;            // 0..255
          int hw = (h0 - 1) * 64 + p;
          const __hip_bfloat16* src = (((unsigned)hw) < (unsigned)NM)
              ? (yb + (long)hw * NC + ic + scol) : (zeropad + scol % 8);
          GLDS16(src, Bs + (wid * 64 + t * 16) * 32);
        }
      }
      // stage A: taps r = 3g .. 3g+2, rows m0..m0+127, cols ic..ic+31
      #pragma unroll
      for (int t = 0; t < 3; t++) {
        int r = g * 3 + t;
        #pragma unroll
        for (int t2 = 0; t2 < 2; t2++) {
          GLDS16(Wt + ((long)r * 512 + m0 + wid * 32 + t2 * 16 + lrow) * 512 + ic + scol,
                 As3 + (t * 128 + wid * 32 + t2 * 16) * 32);
        }
      }
      __builtin_amdgcn_s_waitcnt(0);
      __syncthreads();
      const int dy = g - 1;
      #pragma unroll
      for (int t = 0; t < 3; t++) {          // dx = t-1
        const int dx = t - 1;
        s16x8 bfr[4];
        #pragma unroll
        for (int j = 0; j < 4; j++) {
          int nl = wn + j * 16 + l16;
          int wq_ = nl & 63, hr = nl >> 6;
          int wp = wq_ + dx;
          bool v = ((unsigned)wp) < 64u;     // w-boundary mask
          int p = v ? ((hr + 1 + dy) * 64 + wp) : 0;
          s16x8 tt = *(const s16x8*)(&Bs[p * 32 + quad * 8]);
          bfr[j] = v ? tt : zero8;
        }
        #pragma unroll
        for (int i = 0; i < 4; i++) {
          s16x8 af = *(const s16x8*)(&As3[(t * 128 + wm + i * 16 + l16) * 32 + quad * 8]);
          #pragma unroll
          for (int j = 0; j < 4; j++)
            acc[i][j] = __builtin_amdgcn_mfma_f32_16x16x32_bf16(af, bfr[j], acc[i][j], 0, 0, 0);
        }
      }
    }
  }
  __hip_bfloat16* Cb = q2 + (long)b * NC * NM;
  #pragma unroll
  for (int i = 0; i < 4; i++) {
    #pragma unroll
    for (int j = 0; j < 4; j++) {
      int rbase = m0 + wm + i * 16 + quad * 4;
      int col = n0 + wn + j * 16 + l16;
      #pragma unroll
      for (int r = 0; r < 4; r++)
        Cb[(long)(rbase + r) * NM + col] = __float2bfloat16(acc[i][j][r]);
    }
  }
}

// ---------------- per-row L2 norm (4096 bf16/row) -> max(sqrt(sumsq), 1e-12) ----------------
__global__ __launch_bounds__(256) void rowsumsq(
    const __hip_bfloat16* __restrict__ X, float* __restrict__ out)
{
  long row = blockIdx.x;
  const __hip_bfloat16* p = X + row * (long)NM + threadIdx.x * 16;
  union { i32x4 v; unsigned short u[8]; } a, b;
  a.v = *(const i32x4*)(p);
  b.v = *(const i32x4*)(p + 8);
  float s = 0.f;
  #pragma unroll
  for (int t = 0; t < 8; t++) {
    float f0 = b2f(a.u[t]); s += f0 * f0;
    float f1 = b2f(b.u[t]); s += f1 * f1;
  }
  #pragma unroll
  for (int off = 32; off > 0; off >>= 1) s += __shfl_down(s, off);
  __shared__ float red[4];
  if ((threadIdx.x & 63) == 0) red[threadIdx.x >> 6] = s;
  __syncthreads();
  if (threadIdx.x == 0)
    out[row] = fmaxf(sqrtf(red[0] + red[1] + red[2] + red[3]), 1e-12f);
}

// ---------------- attention logits partial: Gpart[b,h,mc][c][d] over m-chunk ----------------
__global__ __launch_bounds__(256) void attn_g(
    const __hip_bfloat16* __restrict__ q2, const __hip_bfloat16* __restrict__ Kb,
    float* __restrict__ Gpart)
{
  const int mc = blockIdx.x, h = blockIdx.y, b = blockIdx.z;
  const __hip_bfloat16* qrow = q2 + ((long)b * NC + h * 64) * NM + mc * 512;
  const __hip_bfloat16* krow = Kb + ((long)b * NC + h * 64) * NM + mc * 512;
  __shared__ __hip_bfloat16 Qs[64 * 40];
  __shared__ __hip_bfloat16 Ks[64 * 40];
  const int tid = threadIdx.x;
  const int wid = tid >> 6, lane = tid & 63;
  const int wc = (wid >> 1) * 32, wd = (wid & 1) * 32;
  const int quad = lane >> 4, l16 = lane & 15;
  const int srow = tid >> 2, scol = (tid & 3) * 8;
  f32x4 acc[2][2] = {};
  for (int k0 = 0; k0 < 512; k0 += 32) {
    __syncthreads();
    *(i32x4*)(&Qs[srow * 40 + scol]) = *(const i32x4*)(&qrow[(long)srow * NM + k0 + scol]);
    *(i32x4*)(&Ks[srow * 40 + scol]) = *(const i32x4*)(&krow[(long)srow * NM + k0 + scol]);
    __syncthreads();
    s16x8 bfr[2];
    #pragma unroll
    for (int j = 0; j < 2; j++)
      bfr[j] = *(const s16x8*)(&Ks[(wd + j * 16 + l16) * 40 + quad * 8]);
    #pragma unroll
    for (int i = 0; i < 2; i++) {
      s16x8 af = *(const s16x8*)(&Qs[(wc + i * 16 + l16) * 40 + quad * 8]);
      #pragma unroll
      for (int j = 0; j < 2; j++)
        acc[i][j] = __builtin_amdgcn_mfma_f32_16x16x32_bf16(af, bfr[j], acc[i][j], 0, 0, 0);
    }
  }
  float* gp = Gpart + ((long)((b * 8 + h) * 8 + mc)) * 4096;
  #pragma unroll
  for (int i = 0; i < 2; i++)
    #pragma unroll
    for (int j = 0; j < 2; j++)
      #pragma unroll
      for (int r = 0; r < 4; r++)
        gp[(wc + i * 16 + quad * 4 + r) * 64 + wd + j * 16 + l16] = acc[i][j][r];
}

// ---------------- sum partials, normalize, temperature, softmax over d ----------------
__global__ __launch_bounds__(256) void softmax_attn(
    const float* __restrict__ Gpart, const float* __restrict__ qn,
    const float* __restrict__ kn, const float* __restrict__ temp,
    float* __restrict__ attn)
{
  const int h = blockIdx.x, b = blockIdx.y;
  __shared__ float G[64][64];
  const int tid = threadIdx.x;
  const float tv = temp[h];
  for (int e = tid; e < 4096; e += 256) {
    float s = 0.f;
    #pragma unroll
    for (int p = 0; p < 8; p++)
      s += Gpart[((long)((b * 8 + h) * 8 + p)) * 4096 + e];
    int c = e >> 6, d = e & 63;
    float scale = tv / (qn[b * 512 + h * 64 + c] * kn[b * 512 + h * 64 + d]);
    G[c][d] = s * scale;
  }
  __syncthreads();
  int row = tid >> 2, s4 = tid & 3;
  float mx = -1e30f;
  for (int d = s4; d < 64; d += 4) mx = fmaxf(mx, G[row][d]);
  mx = fmaxf(mx, __shfl_xor(mx, 1));
  mx = fmaxf(mx, __shfl_xor(mx, 2));
  float sum = 0.f;
  for (int d = s4; d < 64; d += 4) { float e = __expf(G[row][d] - mx); G[row][d] = e; sum += e; }
  sum += __shfl_xor(sum, 1);
  sum += __shfl_xor(sum, 2);
  float inv = 1.f / sum;
  float* ap = attn + ((long)(b * 8 + h)) * 4096;
  for (int d = s4; d < 64; d += 4) ap[row * 64 + d] = G[row][d] * inv;
}

// ---------------- Wa[b][o][h*64+d] = sum_c w_out[o][h*64+c] * attn[b,h,c,d] ----------------
__global__ __launch_bounds__(256) void wa_kernel(
    const float* __restrict__ attn, const float* __restrict__ wout,
    __hip_bfloat16* __restrict__ Wa)
{
  const int oc = blockIdx.x, h = blockIdx.y, b = blockIdx.z;
  __shared__ float At[64][64];
  __shared__ float Wtl[64][65];
  const int tid = threadIdx.x;
  const float* ap = attn + ((long)(b * 8 + h)) * 4096;
  for (int e = tid; e < 4096; e += 256) {
    At[e >> 6][e & 63] = ap[e];
    Wtl[e >> 6][e & 63] = wout[(long)(oc * 64 + (e >> 6)) * 512 + h * 64 + (e & 63)];
  }
  __syncthreads();
  int d = tid & 63, og = tid >> 6;
  #pragma unroll
  for (int k = 0; k < 16; k++) {
    int o = og * 16 + k;
    float s = 0.f;
    #pragma unroll 8
    for (int c = 0; c < 64; c++) s += Wtl[o][c] * At[c][d];
    Wa[((long)b * 512 + oc * 64 + o) * 512 + h * 64 + d] = __float2bfloat16(s);
  }
}

extern "C" void kernel_launch(void* const* d_in, const int* in_sizes, int n_in,
                              void* d_out, int out_size, void* d_ws, size_t ws_size,
                              hipStream_t stream) {
  const float* x    = (const float*)d_in[0];
  const float* y    = (const float*)d_in[1];
  const float* temp = (const float*)d_in[2];
  const float* wkv  = (const float*)d_in[3];
  const float* wq   = (const float*)d_in[4];
  const float* wdw  = (const float*)d_in[5];
  const float* wout = (const float*)d_in[6];
  float* out = (float*)d_out;     // fp32 output

  char* ws = (char*)d_ws;
  const long TEN = 16777216;  // one (4,512,4096) bf16 tensor, bytes
  __hip_bfloat16* xT  = (__hip_bfloat16*)(ws);               // later reused as q2
  __hip_bfloat16* q2  = xT;                                  // alias: xT dead after Vt GEMM
  __hip_bfloat16* yT  = (__hip_bfloat16*)(ws + TEN);         // reused after conv:
  float* Gpart        = (float*)(ws + TEN);                  //   4 MB
  float* attn         = (float*)(ws + TEN + 4194304);        //   512 KB
  __hip_bfloat16* Wa  = (__hip_bfloat16*)(ws + TEN + 4718592);   // 2 MB
  float* knorm        = (float*)(ws + TEN + 6815744);        //   8 KB
  float* qnorm        = (float*)(ws + TEN + 6823936);        //   8 KB
  __hip_bfloat16* Kb  = (__hip_bfloat16*)(ws + 2 * TEN);
  __hip_bfloat16* Vt  = (__hip_bfloat16*)(ws + 3 * TEN);
  __hip_bfloat16* Wfold = (__hip_bfloat16*)(ws + 4 * TEN);               // 4.72 MB [9][512][512]
  __hip_bfloat16* Wr    = (__hip_bfloat16*)(ws + 4 * TEN + 4718592);     // 4.72 MB
  __hip_bfloat16* wkvB  = (__hip_bfloat16*)(ws + 4 * TEN + 9437184);     // 1 MB
  __hip_bfloat16* wqT   = (__hip_bfloat16*)(ws + 4 * TEN + 10485760);    // 512 KB
  __hip_bfloat16* zeropad = (__hip_bfloat16*)(ws + 4 * TEN + 11010048);  // 256 B

  const long S = (long)4096 * 512;  // per-batch tensor stride (elements)
  const long S2 = (long)512 * 512;
  dim3 blk(256);

  hipMemsetAsync(zeropad, 0, 256, stream);
  pack_wdw<<<dim3(9216), blk, 0, stream>>>(wdw, Wr);
  convert_w<<<dim3(3072), blk, 0, stream>>>(wkv, wq, wkvB, wqT);
  transpose_k<<<dim3(64, 8, 8), blk, 0, stream>>>(x, y, xT, yT);
  // Wfold[r][o][c] = sum_c' Wr[r][o][c'] * wqT[c][c']  (fold 1x1 conv into dwconv)
  gemm_bt<<<dim3(4, 4, 9), blk, 0, stream>>>(Wr, S2, wqT, 0L, Wfold, nullptr, S2, 512, 512, 512, 0);
  // K[b][c][m] = w_k . x
  gemm_bt<<<dim3(32, 4, 4), blk, 0, stream>>>(wkvB, 0L, xT, S, Kb, nullptr, S, 512, 4096, 512, 0);
  // Vt[b][m][c] = x^T . w_v^T
  gemm_bt<<<dim3(4, 32, 4), blk, 0, stream>>>(xT, S, wkvB + 512 * 512, 0L, Vt, nullptr, S, 4096, 512, 512, 0);
  // q2[b][o][hw] = conv3x3(y; Wfold)   (interp L==M is identity)
  conv3x3<<<dim3(32, 4, 4), blk, 0, stream>>>(Wfold, yT, zeropad, q2);
  rowsumsq<<<dim3(2048), blk, 0, stream>>>(Kb, knorm);
  rowsumsq<<<dim3(2048), blk, 0, stream>>>(q2, qnorm);
  attn_g<<<dim3(8, 8, 4), blk, 0, stream>>>(q2, Kb, Gpart);
  softmax_attn<<<dim3(8, 4), blk, 0, stream>>>(Gpart, qnorm, knorm, temp, attn);
  wa_kernel<<<dim3(8, 8, 4), blk, 0, stream>>>(attn, wout, Wa);
  // out[b][o][m] = Wa[b] . Vt[b]^T   -> fp32 d_out
  gemm_bt<<<dim3(32, 4, 4), blk, 0, stream>>>(Wa, S2, Vt, S, nullptr, out, S, 512, 4096, 512, 1);
  (void)in_sizes; (void)n_in; (void)out_size; (void)ws_size;
}

// Round 6
// 311.066 us; speedup vs baseline: 1.0981x; 1.0336x over previous
//
#include <hip/hip_runtime.h>
#include <hip/hip_bf16.h>
#include <math.h>

typedef float f32x4 __attribute__((ext_vector_type(4)));
typedef int   i32x4 __attribute__((ext_vector_type(4)));
typedef short s16x8 __attribute__((ext_vector_type(8)));

#define NB 4
#define NC 512
#define NM 4096
#define NHEADS 8

// async global->LDS, 16B per lane, LDS dest = wave-uniform base + lane*16
#define GLDS16(src, dst) __builtin_amdgcn_global_load_lds( \
    (const __attribute__((address_space(1))) void*)(src),  \
    (__attribute__((address_space(3))) void*)(dst), 16, 0, 0)

// ---------------- prep: weight packs/casts + zeropad + zero norm accumulators ----------------
// Wr[r][o][i] = wdw[o][i][r]; wkvB = bf16(wkv); wqT[c][c'] = wq[c'][c];
// zeropad[0..127] = 0 (bf16); norms[0..4095] = 0.f (knorm2[2048] ++ qnorm2[2048])
__global__ __launch_bounds__(256) void prep(
    const float* __restrict__ wdw, const float* __restrict__ wkv,
    const float* __restrict__ wq,
    __hip_bfloat16* __restrict__ Wr, __hip_bfloat16* __restrict__ wkvB,
    __hip_bfloat16* __restrict__ wqT, __hip_bfloat16* __restrict__ zeropad,
    float* __restrict__ norms)
{
  long idx = (long)blockIdx.x * 256 + threadIdx.x;
  if (idx < 2359296) {                       // 9*512*512
    int r = (int)(idx / 262144);
    int rem = (int)(idx % 262144);
    int o = rem >> 9, i = rem & 511;
    Wr[idx] = __float2bfloat16(wdw[((long)o * 512 + i) * 9 + r]);
  } else if (idx < 2883584) {                // + 1024*512
    long j = idx - 2359296;
    wkvB[j] = __float2bfloat16(wkv[j]);
  } else if (idx < 3145728) {                // + 512*512
    long j = idx - 2883584;
    int c = (int)(j >> 9), cp = (int)(j & 511);
    wqT[j] = __float2bfloat16(wq[(long)cp * 512 + c]);
  } else if (idx < 3145856) {
    zeropad[idx - 3145728] = __float2bfloat16(0.f);
  } else if (idx < 3149952) {
    norms[idx - 3145856] = 0.f;
  }
}

// ---------------- transpose fp32 (b,512,4096) -> bf16 (b,4096,512), vectorized ----------------
__global__ __launch_bounds__(256) void transpose_k(
    const float* __restrict__ x, const float* __restrict__ y,
    __hip_bfloat16* __restrict__ xT, __hip_bfloat16* __restrict__ yT)
{
  __shared__ __hip_bfloat16 tile[64][68];
  int z = blockIdx.z;                       // 0..3 x batches, 4..7 y batches
  const float* src = ((z < 4) ? x : y) + (long)(z & 3) * ((long)NC * NM);
  __hip_bfloat16* dst = (z < 4 ? xT : yT) + (long)(z & 3) * ((long)NC * NM);
  int tm = blockIdx.x * 64, tc = blockIdx.y * 64;
  int tx4 = threadIdx.x & 15, trow = threadIdx.x >> 4;
  #pragma unroll
  for (int p = 0; p < 4; p++) {
    int crow = trow + p * 16;
    f32x4 v = *(const f32x4*)&src[(long)(tc + crow) * NM + tm + tx4 * 4];
    #pragma unroll
    for (int t = 0; t < 4; t++) tile[crow][tx4 * 4 + t] = __float2bfloat16(v[t]);
  }
  __syncthreads();
  #pragma unroll
  for (int p = 0; p < 4; p++) {
    int mrow = trow + p * 16;
    union { ushort4 u4; unsigned short u[4]; } o;
    #pragma unroll
    for (int t = 0; t < 4; t++)
      o.u[t] = *(const unsigned short*)&tile[tx4 * 4 + t][mrow];
    *(ushort4*)&dst[(long)(tm + mrow) * NC + tc + tx4 * 4] = o.u4;
  }
}

// ---------------- generic GEMM: C[M,N] = A[M,K] * B[N,K]^T (row-major bf16, fp32 acc) ----------------
__global__ __launch_bounds__(256) void gemm_bt(
    const __hip_bfloat16* __restrict__ Aall, long sA,
    const __hip_bfloat16* __restrict__ Ball, long sB,
    __hip_bfloat16* __restrict__ Cball, float* __restrict__ Cfall, long sC,
    int M, int N, int Kd, int outF32)
{
  const __hip_bfloat16* A = Aall + (long)blockIdx.z * sA;
  const __hip_bfloat16* B = Ball + (long)blockIdx.z * sB;
  const int m0 = blockIdx.y * 128, n0 = blockIdx.x * 128;
  __shared__ __hip_bfloat16 As[128 * 32];
  __shared__ __hip_bfloat16 Bs[128 * 32];
  const int tid = threadIdx.x;
  const int wid = tid >> 6, lane = tid & 63;
  const int wm = (wid >> 1) * 64, wn = (wid & 1) * 64;
  const int quad = lane >> 4, l16 = lane & 15;
  const int srow = wid * 32 + (lane >> 2);
  const int scol = (lane & 3) * 8;
  f32x4 acc[4][4] = {};
  for (int k0 = 0; k0 < Kd; k0 += 32) {
    __syncthreads();
    #pragma unroll
    for (int t = 0; t < 2; t++) {
      GLDS16(A + (long)(m0 + srow + t * 16) * Kd + k0 + scol,
             As + (wid * 32 + t * 16) * 32);
      GLDS16(B + (long)(n0 + srow + t * 16) * Kd + k0 + scol,
             Bs + (wid * 32 + t * 16) * 32);
    }
    __builtin_amdgcn_s_waitcnt(0);
    __syncthreads();
    s16x8 bfr[4];
    #pragma unroll
    for (int j = 0; j < 4; j++)
      bfr[j] = *(const s16x8*)(&Bs[(wn + j * 16 + l16) * 32 + quad * 8]);
    #pragma unroll
    for (int i = 0; i < 4; i++) {
      s16x8 af = *(const s16x8*)(&As[(wm + i * 16 + l16) * 32 + quad * 8]);
      #pragma unroll
      for (int j = 0; j < 4; j++)
        acc[i][j] = __builtin_amdgcn_mfma_f32_16x16x32_bf16(af, bfr[j], acc[i][j], 0, 0, 0);
    }
  }
  if (outF32) {
    float* C = Cfall + (long)blockIdx.z * sC;
    #pragma unroll
    for (int i = 0; i < 4; i++)
      #pragma unroll
      for (int j = 0; j < 4; j++) {
        int rbase = m0 + wm + i * 16 + quad * 4;
        int col = n0 + wn + j * 16 + l16;
        #pragma unroll
        for (int r = 0; r < 4; r++)
          C[(long)(rbase + r) * N + col] = acc[i][j][r];
      }
  } else {
    __hip_bfloat16* C = Cball + (long)blockIdx.z * sC;
    #pragma unroll
    for (int i = 0; i < 4; i++)
      #pragma unroll
      for (int j = 0; j < 4; j++) {
        int rbase = m0 + wm + i * 16 + quad * 4;
        int col = n0 + wn + j * 16 + l16;
        #pragma unroll
        for (int r = 0; r < 4; r++)
          C[(long)(rbase + r) * N + col] = __float2bfloat16(acc[i][j][r]);
      }
  }
}

// ---------------- merged K/V GEMM, one launch (z<4: K c-major + knorm2; z>=4: V m-major) ----------------
__global__ __launch_bounds__(256) void gemm_kv(
    const __hip_bfloat16* __restrict__ wkvB,
    const __hip_bfloat16* __restrict__ xT,
    __hip_bfloat16* __restrict__ Kb,
    __hip_bfloat16* __restrict__ Vt,
    float* __restrict__ knorm2)
{
  const int z = blockIdx.z;
  const int b = z & 3;
  const bool kmode = (z < 4);
  const long S = (long)NM * NC;
  const __hip_bfloat16* A = kmode ? wkvB : (xT + b * S);
  const __hip_bfloat16* B = kmode ? (xT + b * S) : (wkvB + 262144);
  __hip_bfloat16* C = kmode ? (Kb + b * S) : (Vt + b * S);
  const int m0 = (kmode ? blockIdx.y : blockIdx.x) * 128;
  const int n0 = (kmode ? blockIdx.x : blockIdx.y) * 128;
  const int N = kmode ? NM : NC;
  __shared__ __hip_bfloat16 As[128 * 32];
  __shared__ __hip_bfloat16 Bs[128 * 32];
  const int tid = threadIdx.x;
  const int wid = tid >> 6, lane = tid & 63;
  const int wm = (wid >> 1) * 64, wn = (wid & 1) * 64;
  const int quad = lane >> 4, l16 = lane & 15;
  const int srow = wid * 32 + (lane >> 2);
  const int scol = (lane & 3) * 8;
  f32x4 acc[4][4] = {};
  for (int k0 = 0; k0 < NC; k0 += 32) {
    __syncthreads();
    #pragma unroll
    for (int t = 0; t < 2; t++) {
      GLDS16(A + (long)(m0 + srow + t * 16) * NC + k0 + scol,
             As + (wid * 32 + t * 16) * 32);
      GLDS16(B + (long)(n0 + srow + t * 16) * NC + k0 + scol,
             Bs + (wid * 32 + t * 16) * 32);
    }
    __builtin_amdgcn_s_waitcnt(0);
    __syncthreads();
    s16x8 bfr[4];
    #pragma unroll
    for (int j = 0; j < 4; j++)
      bfr[j] = *(const s16x8*)(&Bs[(wn + j * 16 + l16) * 32 + quad * 8]);
    #pragma unroll
    for (int i = 0; i < 4; i++) {
      s16x8 af = *(const s16x8*)(&As[(wm + i * 16 + l16) * 32 + quad * 8]);
      #pragma unroll
      for (int j = 0; j < 4; j++)
        acc[i][j] = __builtin_amdgcn_mfma_f32_16x16x32_bf16(af, bfr[j], acc[i][j], 0, 0, 0);
    }
  }
  #pragma unroll
  for (int i = 0; i < 4; i++)
    #pragma unroll
    for (int j = 0; j < 4; j++) {
      int rbase = m0 + wm + i * 16 + quad * 4;
      int col = n0 + wn + j * 16 + l16;
      #pragma unroll
      for (int r = 0; r < 4; r++)
        C[(long)(rbase + r) * N + col] = __float2bfloat16(acc[i][j][r]);
    }
  if (kmode) {     // knorm2[b*512 + c] += sum over this tile's m-cols of K[c,m]^2
    #pragma unroll
    for (int i = 0; i < 4; i++) {
      int rbase = m0 + wm + i * 16 + quad * 4;
      #pragma unroll
      for (int r = 0; r < 4; r++) {
        float s = 0.f;
        #pragma unroll
        for (int j = 0; j < 4; j++) s += acc[i][j][r] * acc[i][j][r];
        s += __shfl_xor(s, 1); s += __shfl_xor(s, 2);
        s += __shfl_xor(s, 4); s += __shfl_xor(s, 8);
        if (l16 == 0) atomicAdd(&knorm2[b * 512 + rbase + r], s);
      }
    }
  }
}

// ---------------- 3x3 conv as implicit GEMM (w_q folded), + qnorm2 partials ----------------
__global__ __launch_bounds__(256) void conv3x3(
    const __hip_bfloat16* __restrict__ Wt,   // [9][512][512] folded weights
    const __hip_bfloat16* __restrict__ yT,   // [b][4096][512]
    const __hip_bfloat16* __restrict__ zeropad,
    __hip_bfloat16* __restrict__ q2,         // [b][512][4096]
    float* __restrict__ qnorm2)
{
  const int b = blockIdx.z;
  const int n0 = blockIdx.x * 128;   // hw tile (2 image rows)
  const int m0 = blockIdx.y * 128;   // o tile
  __shared__ __hip_bfloat16 As3[3 * 128 * 32];
  __shared__ __hip_bfloat16 Bs[256 * 32];
  const int tid = threadIdx.x;
  const int wid = tid >> 6, lane = tid & 63;
  const int wm = (wid >> 1) * 64, wn = (wid & 1) * 64;
  const int quad = lane >> 4, l16 = lane & 15;
  const int lrow = lane >> 2, scol = (lane & 3) * 8;
  const int h0 = n0 >> 6;
  const __hip_bfloat16* yb = yT + (long)b * NM * NC;
  f32x4 acc[4][4] = {};
  const s16x8 zero8 = {0, 0, 0, 0, 0, 0, 0, 0};

  for (int ic = 0; ic < 512; ic += 32) {
    #pragma unroll
    for (int g = 0; g < 3; g++) {            // dy = g-1
      __syncthreads();
      if (g == 0) {
        #pragma unroll
        for (int t = 0; t < 4; t++) {
          int p = wid * 64 + t * 16 + lrow;
          int hw = (h0 - 1) * 64 + p;
          const __hip_bfloat16* src = (((unsigned)hw) < (unsigned)NM)
              ? (yb + (long)hw * NC + ic + scol) : (zeropad + scol % 8);
          GLDS16(src, Bs + (wid * 64 + t * 16) * 32);
        }
      }
      #pragma unroll
      for (int t = 0; t < 3; t++) {
        int r = g * 3 + t;
        #pragma unroll
        for (int t2 = 0; t2 < 2; t2++) {
          GLDS16(Wt + ((long)r * 512 + m0 + wid * 32 + t2 * 16 + lrow) * 512 + ic + scol,
                 As3 + (t * 128 + wid * 32 + t2 * 16) * 32);
        }
      }
      __builtin_amdgcn_s_waitcnt(0);
      __syncthreads();
      const int dy = g - 1;
      #pragma unroll
      for (int t = 0; t < 3; t++) {          // dx = t-1
        const int dx = t - 1;
        s16x8 bfr[4];
        #pragma unroll
        for (int j = 0; j < 4; j++) {
          int nl = wn + j * 16 + l16;
          int wq_ = nl & 63, hr = nl >> 6;
          int wp = wq_ + dx;
          bool v = ((unsigned)wp) < 64u;
          int p = v ? ((hr + 1 + dy) * 64 + wp) : 0;
          s16x8 tt = *(const s16x8*)(&Bs[p * 32 + quad * 8]);
          bfr[j] = v ? tt : zero8;
        }
        #pragma unroll
        for (int i = 0; i < 4; i++) {
          s16x8 af = *(const s16x8*)(&As3[(t * 128 + wm + i * 16 + l16) * 32 + quad * 8]);
          #pragma unroll
          for (int j = 0; j < 4; j++)
            acc[i][j] = __builtin_amdgcn_mfma_f32_16x16x32_bf16(af, bfr[j], acc[i][j], 0, 0, 0);
        }
      }
    }
  }
  __hip_bfloat16* Cb = q2 + (long)b * NC * NM;
  #pragma unroll
  for (int i = 0; i < 4; i++)
    #pragma unroll
    for (int j = 0; j < 4; j++) {
      int rbase = m0 + wm + i * 16 + quad * 4;
      int col = n0 + wn + j * 16 + l16;
      #pragma unroll
      for (int r = 0; r < 4; r++)
        Cb[(long)(rbase + r) * NM + col] = __float2bfloat16(acc[i][j][r]);
    }
  // qnorm2[b*512 + o] += sum over this tile's hw-cols of q2[o,hw]^2
  #pragma unroll
  for (int i = 0; i < 4; i++) {
    int rbase = m0 + wm + i * 16 + quad * 4;
    #pragma unroll
    for (int r = 0; r < 4; r++) {
      float s = 0.f;
      #pragma unroll
      for (int j = 0; j < 4; j++) s += acc[i][j][r] * acc[i][j][r];
      s += __shfl_xor(s, 1); s += __shfl_xor(s, 2);
      s += __shfl_xor(s, 4); s += __shfl_xor(s, 8);
      if (l16 == 0) atomicAdd(&qnorm2[b * 512 + rbase + r], s);
    }
  }
}

// ---------------- attention logits partial: Gpart[b,h,mc][c][d] over m-chunk ----------------
__global__ __launch_bounds__(256) void attn_g(
    const __hip_bfloat16* __restrict__ q2, const __hip_bfloat16* __restrict__ Kb,
    float* __restrict__ Gpart)
{
  const int mc = blockIdx.x, h = blockIdx.y, b = blockIdx.z;
  const __hip_bfloat16* qrow = q2 + ((long)b * NC + h * 64) * NM + mc * 512;
  const __hip_bfloat16* krow = Kb + ((long)b * NC + h * 64) * NM + mc * 512;
  __shared__ __hip_bfloat16 Qs[64 * 40];
  __shared__ __hip_bfloat16 Ks[64 * 40];
  const int tid = threadIdx.x;
  const int wid = tid >> 6, lane = tid & 63;
  const int wc = (wid >> 1) * 32, wd = (wid & 1) * 32;
  const int quad = lane >> 4, l16 = lane & 15;
  const int srow = tid >> 2, scol = (tid & 3) * 8;
  f32x4 acc[2][2] = {};
  for (int k0 = 0; k0 < 512; k0 += 32) {
    __syncthreads();
    *(i32x4*)(&Qs[srow * 40 + scol]) = *(const i32x4*)(&qrow[(long)srow * NM + k0 + scol]);
    *(i32x4*)(&Ks[srow * 40 + scol]) = *(const i32x4*)(&krow[(long)srow * NM + k0 + scol]);
    __syncthreads();
    s16x8 bfr[2];
    #pragma unroll
    for (int j = 0; j < 2; j++)
      bfr[j] = *(const s16x8*)(&Ks[(wd + j * 16 + l16) * 40 + quad * 8]);
    #pragma unroll
    for (int i = 0; i < 2; i++) {
      s16x8 af = *(const s16x8*)(&Qs[(wc + i * 16 + l16) * 40 + quad * 8]);
      #pragma unroll
      for (int j = 0; j < 2; j++)
        acc[i][j] = __builtin_amdgcn_mfma_f32_16x16x32_bf16(af, bfr[j], acc[i][j], 0, 0, 0);
    }
  }
  float* gp = Gpart + ((long)((b * 8 + h) * 8 + mc)) * 4096;
  #pragma unroll
  for (int i = 0; i < 2; i++)
    #pragma unroll
    for (int j = 0; j < 2; j++)
      #pragma unroll
      for (int r = 0; r < 4; r++)
        gp[(wc + i * 16 + quad * 4 + r) * 64 + wd + j * 16 + l16] = acc[i][j][r];
}

// ---------------- fused: sum partials -> normalize -> softmax -> Wa = (wout chunk) . attn ----------------
__global__ __launch_bounds__(256) void softmax_wa(
    const float* __restrict__ Gpart, const float* __restrict__ qnorm2,
    const float* __restrict__ knorm2, const float* __restrict__ temp,
    const float* __restrict__ wout, __hip_bfloat16* __restrict__ Wa)
{
  const int oc = blockIdx.x, h = blockIdx.y, b = blockIdx.z;
  __shared__ float G[64][64];
  __shared__ float Wt[64][65];
  const int tid = threadIdx.x;
  const float tv = temp[h];
  for (int e = tid; e < 4096; e += 256) {
    float s = 0.f;
    #pragma unroll
    for (int p = 0; p < 8; p++)
      s += Gpart[((long)((b * 8 + h) * 8 + p)) * 4096 + e];
    int c = e >> 6, d = e & 63;
    float qn = fmaxf(sqrtf(qnorm2[b * 512 + h * 64 + c]), 1e-12f);
    float kn = fmaxf(sqrtf(knorm2[b * 512 + h * 64 + d]), 1e-12f);
    G[c][d] = s * tv / (qn * kn);
    Wt[c][d] = wout[(long)(oc * 64 + c) * 512 + h * 64 + d];
  }
  __syncthreads();
  int row = tid >> 2, s4 = tid & 3;
  float mx = -1e30f;
  for (int d = s4; d < 64; d += 4) mx = fmaxf(mx, G[row][d]);
  mx = fmaxf(mx, __shfl_xor(mx, 1));
  mx = fmaxf(mx, __shfl_xor(mx, 2));
  float sum = 0.f;
  for (int d = s4; d < 64; d += 4) { float e = __expf(G[row][d] - mx); G[row][d] = e; sum += e; }
  sum += __shfl_xor(sum, 1);
  sum += __shfl_xor(sum, 2);
  float inv = 1.f / sum;
  for (int d = s4; d < 64; d += 4) G[row][d] *= inv;
  __syncthreads();
  int d = tid & 63, og = tid >> 6;
  #pragma unroll
  for (int k2 = 0; k2 < 16; k2++) {
    int o = og * 16 + k2;
    float s = 0.f;
    #pragma unroll 8
    for (int c = 0; c < 64; c++) s += Wt[o][c] * G[c][d];
    Wa[((long)b * 512 + oc * 64 + o) * 512 + h * 64 + d] = __float2bfloat16(s);
  }
}

extern "C" void kernel_launch(void* const* d_in, const int* in_sizes, int n_in,
                              void* d_out, int out_size, void* d_ws, size_t ws_size,
                              hipStream_t stream) {
  const float* x    = (const float*)d_in[0];
  const float* y    = (const float*)d_in[1];
  const float* temp = (const float*)d_in[2];
  const float* wkv  = (const float*)d_in[3];
  const float* wq   = (const float*)d_in[4];
  const float* wdw  = (const float*)d_in[5];
  const float* wout = (const float*)d_in[6];
  float* out = (float*)d_out;     // fp32 output

  char* ws = (char*)d_ws;
  const long TEN = 16777216;  // one (4,512,4096) bf16 tensor, bytes
  __hip_bfloat16* xT  = (__hip_bfloat16*)(ws);               // reused as q2 after kv GEMM
  __hip_bfloat16* q2  = xT;
  __hip_bfloat16* yT  = (__hip_bfloat16*)(ws + TEN);         // reused after conv:
  float* Gpart        = (float*)(ws + TEN);                  //   4 MB
  __hip_bfloat16* Wa  = (__hip_bfloat16*)(ws + TEN + 4718592);   // 2 MB
  __hip_bfloat16* Kb  = (__hip_bfloat16*)(ws + 2 * TEN);
  __hip_bfloat16* Vt  = (__hip_bfloat16*)(ws + 3 * TEN);
  __hip_bfloat16* Wfold = (__hip_bfloat16*)(ws + 4 * TEN);               // 4.72 MB
  __hip_bfloat16* Wr    = (__hip_bfloat16*)(ws + 4 * TEN + 4718592);     // 4.72 MB
  __hip_bfloat16* wkvB  = (__hip_bfloat16*)(ws + 4 * TEN + 9437184);     // 1 MB
  __hip_bfloat16* wqT   = (__hip_bfloat16*)(ws + 4 * TEN + 10485760);    // 512 KB
  __hip_bfloat16* zeropad = (__hip_bfloat16*)(ws + 4 * TEN + 11010048);  // 256 B
  float* norms          = (float*)(ws + 4 * TEN + 11010304);             // 16 KB
  float* knorm2 = norms;
  float* qnorm2 = norms + 2048;

  const long S = (long)4096 * 512;
  const long S2 = (long)512 * 512;
  dim3 blk(256);

  prep<<<dim3(12305), blk, 0, stream>>>(wdw, wkv, wq, Wr, wkvB, wqT, zeropad, norms);
  transpose_k<<<dim3(64, 8, 8), blk, 0, stream>>>(x, y, xT, yT);
  // Wfold[r][o][c] = sum_c' Wr[r][o][c'] * wqT[c][c']
  gemm_bt<<<dim3(4, 4, 9), blk, 0, stream>>>(Wr, S2, wqT, 0L, Wfold, nullptr, S2, 512, 512, 512, 0);
  // K[b][c][m] (+knorm2) and Vt[b][m][c], one launch
  gemm_kv<<<dim3(32, 4, 8), blk, 0, stream>>>(wkvB, xT, Kb, Vt, knorm2);
  // q2[b][o][hw] = conv3x3(y; Wfold)  (+qnorm2)
  conv3x3<<<dim3(32, 4, 4), blk, 0, stream>>>(Wfold, yT, zeropad, q2, qnorm2);
  attn_g<<<dim3(8, 8, 4), blk, 0, stream>>>(q2, Kb, Gpart);
  softmax_wa<<<dim3(8, 8, 4), blk, 0, stream>>>(Gpart, qnorm2, knorm2, temp, wout, Wa);
  // out[b][o][m] = Wa[b] . Vt[b]^T   -> fp32 d_out
  gemm_bt<<<dim3(32, 4, 4), blk, 0, stream>>>(Wa, S2, Vt, S, nullptr, out, S, 512, 4096, 512, 1);
  (void)in_sizes; (void)n_in; (void)out_size; (void)ws_size;
}